// Round 1
// baseline (522.163 us; speedup 1.0000x reference)
//
#include <hip/hip_runtime.h>

// SlidingKernelAttention: unfold(k=4,s=1) -> per-(b,c,patch-offset) attention
// over seq=256 tokens of dim=16 -> overlap-add fold.
// B=2, C=64, H=W=67, Ho=Wo=64, N = B*C*16 = 2048 independent sequences.

#define BATCH 2
#define CHAN 64
#define HWDIM 67
#define HOUT 64
#define SEQ 256
#define DIM 16
#define NSEQ 2048            // BATCH*CHAN*16
#define ATT_SCALE 0.70710678118654752f   // (DIM/HEADS)^-0.5 = 2^-0.5

__global__ __launch_bounds__(256) void ska_attn_kernel(
    const float* __restrict__ x,      // [B, C, 67, 67]
    const float* __restrict__ w,      // [48, 16]  (q rows 0..15, k rows 16..31, v rows 32..47)
    float* __restrict__ out)          // [B, C, 67, 67], pre-zeroed
{
    __shared__ float sw[3 * DIM * DIM];   // 48x16 = 768 floats
    __shared__ float sk[SEQ][DIM];        // 16 KB
    __shared__ float sv[SEQ][DIM];        // 16 KB

    const int n  = blockIdx.x;
    const int p  = n & 15;                // patch offset index
    const int bc = n >> 4;                // b*C + c
    const int oi = p >> 2;                // i
    const int oj = p & 3;                 // j

    const int s   = threadIdx.x;          // token id 0..255
    const int ph  = s >> 2;               // image row in [0,64)
    const int pw0 = (s & 3) * DIM;        // image col base in {0,16,32,48}

    // stage w_qkv into LDS (768 floats, 256 threads -> 3 each)
#pragma unroll
    for (int r = 0; r < 3; ++r)
        sw[r * 256 + s] = w[r * 256 + s];

    // load this token's 16 input features (16 consecutive pixels in one row)
    const float* xrow = x + ((size_t)bc * HWDIM + (ph + oi)) * HWDIM + pw0 + oj;
    float xr[DIM];
#pragma unroll
    for (int d = 0; d < DIM; ++d) xr[d] = xrow[d];

    __syncthreads();   // sw ready

    // qkv projection: q kept in registers, k/v to LDS
    float q[DIM];
#pragma unroll
    for (int o = 0; o < DIM; ++o) {
        float aq = 0.f, ak = 0.f, av = 0.f;
#pragma unroll
        for (int d = 0; d < DIM; ++d) {
            aq += xr[d] * sw[o * DIM + d];
            ak += xr[d] * sw[(DIM + o) * DIM + d];
            av += xr[d] * sw[(2 * DIM + o) * DIM + d];
        }
        q[o]     = aq * ATT_SCALE;   // fold scale into q
        sk[s][o] = ak;
        sv[s][o] = av;
    }
    __syncthreads();   // sk/sv ready

    // attention: softmax without max-subtraction (scores bounded, fp32 safe)
    float l = 0.f;
    float acc[DIM];
#pragma unroll
    for (int d = 0; d < DIM; ++d) acc[d] = 0.f;

    for (int t = 0; t < SEQ; ++t) {
        float sc = 0.f;
#pragma unroll
        for (int d = 0; d < DIM; ++d) sc += q[d] * sk[t][d];
        const float pe = __expf(sc);
        l += pe;
#pragma unroll
        for (int d = 0; d < DIM; ++d) acc[d] += pe * sv[t][d];
    }

    const float rl = 1.f / l;

    // fold (overlap-add): out[bc, ph+oi, pw0+d+oj] += acc[d]/l
    float* obase = out + ((size_t)bc * HWDIM + (ph + oi)) * HWDIM + pw0 + oj;
#pragma unroll
    for (int d = 0; d < DIM; ++d)
        atomicAdd(&obase[d], acc[d] * rl);
}

extern "C" void kernel_launch(void* const* d_in, const int* in_sizes, int n_in,
                              void* d_out, int out_size, void* d_ws, size_t ws_size,
                              hipStream_t stream) {
    const float* x = (const float*)d_in[0];
    const float* w = (const float*)d_in[1];
    float* out = (float*)d_out;

    // harness poisons d_out with 0xAA; fold accumulates, so zero it first
    hipMemsetAsync(out, 0, (size_t)out_size * sizeof(float), stream);

    ska_attn_kernel<<<NSEQ, 256, 0, stream>>>(x, w, out);
}

// Round 2
// 236.113 us; speedup vs baseline: 2.2115x; 2.2115x over previous
//
#include <hip/hip_runtime.h>

// SlidingKernelAttention: unfold(k=4,s=1) -> per-(b,c,patch-offset) attention
// over seq=256 tokens of dim=16 -> overlap-add fold.
// B=2, C=64, H=W=67, Ho=Wo=64, N = B*C*16 = 2048 independent sequences.
//
// R2: two-pass. Pass 1 writes attention outputs ao[n][64][64] to d_ws
// (coalesced, no atomics). Pass 2 folds by pure gather: the flat token
// index algebra gives s*16+d == (h-i)*64 + (w-j), so each (i,j) plane of
// ao is a linear 64x64 image and the fold is 16 coalesced reads per pixel.
// R1 counters showed 256 MiB of atomic write traffic (32B/atomic) = the
// bottleneck; this removes all atomics.

#define BATCH 2
#define CHAN 64
#define HWDIM 67
#define SEQ 256
#define DIM 16
#define NSEQ 2048            // BATCH*CHAN*16
#define PLANE 4096           // 64*64 floats per sequence
#define OUT_TOTAL (BATCH * CHAN * HWDIM * HWDIM)   // 574592
#define ATT_SCALE 0.70710678118654752f   // (DIM/HEADS)^-0.5 = 2^-0.5

__global__ __launch_bounds__(256) void ska_attn_pass1(
    const float* __restrict__ x,      // [B, C, 67, 67]
    const float* __restrict__ w,      // [48, 16]
    float* __restrict__ ao)           // [NSEQ, 64, 64] workspace
{
    __shared__ float sw[3 * DIM * DIM];   // 48x16 = 768 floats
    __shared__ float sk[SEQ][DIM];        // 16 KB
    __shared__ float sv[SEQ][DIM];        // 16 KB

    const int n  = blockIdx.x;
    const int p  = n & 15;                // patch offset index
    const int bc = n >> 4;                // b*C + c
    const int oi = p >> 2;                // i
    const int oj = p & 3;                 // j

    const int s   = threadIdx.x;          // token id 0..255
    const int ph  = s >> 2;               // image row in [0,64)
    const int pw0 = (s & 3) * DIM;        // image col base in {0,16,32,48}

#pragma unroll
    for (int r = 0; r < 3; ++r)
        sw[r * 256 + s] = w[r * 256 + s];

    const float* xrow = x + ((size_t)bc * HWDIM + (ph + oi)) * HWDIM + pw0 + oj;
    float xr[DIM];
#pragma unroll
    for (int d = 0; d < DIM; ++d) xr[d] = xrow[d];

    __syncthreads();   // sw ready

    float q[DIM];
#pragma unroll
    for (int o = 0; o < DIM; ++o) {
        float aq = 0.f, ak = 0.f, av = 0.f;
#pragma unroll
        for (int d = 0; d < DIM; ++d) {
            aq += xr[d] * sw[o * DIM + d];
            ak += xr[d] * sw[(DIM + o) * DIM + d];
            av += xr[d] * sw[(2 * DIM + o) * DIM + d];
        }
        q[o]     = aq * ATT_SCALE;
        sk[s][o] = ak;
        sv[s][o] = av;
    }
    __syncthreads();   // sk/sv ready

    // softmax without max-subtraction (scores bounded, fp32-safe)
    float l = 0.f;
    float acc[DIM];
#pragma unroll
    for (int d = 0; d < DIM; ++d) acc[d] = 0.f;

    for (int t = 0; t < SEQ; ++t) {
        float sc = 0.f;
#pragma unroll
        for (int d = 0; d < DIM; ++d) sc += q[d] * sk[t][d];
        const float pe = __expf(sc);
        l += pe;
#pragma unroll
        for (int d = 0; d < DIM; ++d) acc[d] += pe * sv[t][d];
    }

    const float rl = 1.f / l;

    // coalesced store: ao[n][s*16 + d]  (== ao-plane[h-i][w-j] linear image)
    float4* obase = (float4*)(ao + (size_t)n * PLANE + s * DIM);
#pragma unroll
    for (int d4 = 0; d4 < 4; ++d4) {
        float4 v4;
        v4.x = acc[d4 * 4 + 0] * rl;
        v4.y = acc[d4 * 4 + 1] * rl;
        v4.z = acc[d4 * 4 + 2] * rl;
        v4.w = acc[d4 * 4 + 3] * rl;
        obase[d4] = v4;
    }
}

__global__ __launch_bounds__(256) void ska_fold_pass2(
    const float* __restrict__ ao,     // [NSEQ, 64, 64]
    float* __restrict__ out)          // [B, C, 67, 67]
{
    const int idx = blockIdx.x * 256 + threadIdx.x;
    if (idx >= OUT_TOTAL) return;
    const int w  = idx % HWDIM;
    const int t  = idx / HWDIM;
    const int h  = t % HWDIM;
    const int bc = t / HWDIM;

    const float* base = ao + (size_t)bc * 16 * PLANE;
    float acc = 0.f;
#pragma unroll
    for (int i = 0; i < 4; ++i) {
        const int ph = h - i;
        if (ph < 0 || ph >= 64) continue;
#pragma unroll
        for (int j = 0; j < 4; ++j) {
            const int pw = w - j;
            if (pw < 0 || pw >= 64) continue;
            acc += base[(i * 4 + j) * PLANE + ph * 64 + pw];
        }
    }
    out[idx] = acc;
}

// ---- fallback (atomic fold) if workspace is too small ----
__global__ __launch_bounds__(256) void ska_attn_atomic(
    const float* __restrict__ x, const float* __restrict__ w,
    float* __restrict__ out)
{
    __shared__ float sw[3 * DIM * DIM];
    __shared__ float sk[SEQ][DIM];
    __shared__ float sv[SEQ][DIM];

    const int n = blockIdx.x, p = n & 15, bc = n >> 4, oi = p >> 2, oj = p & 3;
    const int s = threadIdx.x, ph = s >> 2, pw0 = (s & 3) * DIM;

#pragma unroll
    for (int r = 0; r < 3; ++r) sw[r * 256 + s] = w[r * 256 + s];

    const float* xrow = x + ((size_t)bc * HWDIM + (ph + oi)) * HWDIM + pw0 + oj;
    float xr[DIM];
#pragma unroll
    for (int d = 0; d < DIM; ++d) xr[d] = xrow[d];
    __syncthreads();

    float q[DIM];
#pragma unroll
    for (int o = 0; o < DIM; ++o) {
        float aq = 0.f, ak = 0.f, av = 0.f;
#pragma unroll
        for (int d = 0; d < DIM; ++d) {
            aq += xr[d] * sw[o * DIM + d];
            ak += xr[d] * sw[(DIM + o) * DIM + d];
            av += xr[d] * sw[(2 * DIM + o) * DIM + d];
        }
        q[o] = aq * ATT_SCALE; sk[s][o] = ak; sv[s][o] = av;
    }
    __syncthreads();

    float l = 0.f, acc[DIM];
#pragma unroll
    for (int d = 0; d < DIM; ++d) acc[d] = 0.f;
    for (int t = 0; t < SEQ; ++t) {
        float sc = 0.f;
#pragma unroll
        for (int d = 0; d < DIM; ++d) sc += q[d] * sk[t][d];
        const float pe = __expf(sc);
        l += pe;
#pragma unroll
        for (int d = 0; d < DIM; ++d) acc[d] += pe * sv[t][d];
    }
    const float rl = 1.f / l;
    float* obase = out + ((size_t)bc * HWDIM + (ph + oi)) * HWDIM + pw0 + oj;
#pragma unroll
    for (int d = 0; d < DIM; ++d) atomicAdd(&obase[d], acc[d] * rl);
}

extern "C" void kernel_launch(void* const* d_in, const int* in_sizes, int n_in,
                              void* d_out, int out_size, void* d_ws, size_t ws_size,
                              hipStream_t stream) {
    const float* x = (const float*)d_in[0];
    const float* w = (const float*)d_in[1];
    float* out = (float*)d_out;

    const size_t need = (size_t)NSEQ * PLANE * sizeof(float);   // 33.5 MB
    if (ws_size >= need) {
        float* ao = (float*)d_ws;
        ska_attn_pass1<<<NSEQ, 256, 0, stream>>>(x, w, ao);
        ska_fold_pass2<<<(OUT_TOTAL + 255) / 256, 256, 0, stream>>>(ao, out);
    } else {
        hipMemsetAsync(out, 0, (size_t)out_size * sizeof(float), stream);
        ska_attn_atomic<<<NSEQ, 256, 0, stream>>>(x, w, out);
    }
}

// Round 3
// 116.527 us; speedup vs baseline: 4.4810x; 2.0262x over previous
//
#include <hip/hip_runtime.h>

// SlidingKernelAttention: unfold(k=4,s=1) -> per-(b,c,patch-offset) attention
// over seq=256 tokens of dim=16 -> overlap-add fold.
// B=2, C=64, H=W=67, Ho=Wo=64, N = B*C*16 = 2048 independent sequences.
//
// R3: pass 1 moved to MFMA (v_mfma_f32_16x16x16f16, K=16 == dim, no padding).
// Everything computed transposed: S^T = K.Q^T, O^T = V^T.P^T, because the
// MFMA C/D fragment layout (col=lane&15, row=4*(lane>>4)+reg) is IDENTICAL
// to the B-operand layout -- exp(S^T) feeds the PV MFMA in-register.
// Projection (VALU) writes k/v/q directly in MFMA fragment order to LDS.
// softmax denom: per-lane partial sums + 2-stage shfl_xor butterfly.
// exp via native v_exp_f32: scale*log2(e) folded into q.

#define BATCH 2
#define CHAN 64
#define HWDIM 67
#define SEQ 256
#define DIM 16
#define NSEQ 2048            // BATCH*CHAN*16
#define PLANE 4096           // 64*64 floats per sequence
#define OUT_TOTAL (BATCH * CHAN * HWDIM * HWDIM)   // 574592
#define ATT_SCALE 0.70710678118654752f             // (DIM/HEADS)^-0.5
#define LOG2E 1.44269504088896340736f

typedef _Float16 half4 __attribute__((ext_vector_type(4)));
typedef float float4v __attribute__((ext_vector_type(4)));

__global__ __launch_bounds__(256) void ska_attn_pass1(
    const float* __restrict__ x,      // [B, C, 67, 67]
    const float* __restrict__ w,      // [48, 16]
    float* __restrict__ ao)           // [NSEQ, 64, 64] workspace
{
    __shared__ float sw[3 * DIM * DIM];       // 48x16 = 3 KB
    // MFMA fragment-order staging (f16), per 16-token tile:
    // kA: A-frag of K-tile:  elem (kk,d)  at [kt][kk + 16*(d>>2)][d&3]
    // vA: A-frag of V^T-tile: elem (d,kk) at [kt][d + 16*(kk>>2)][kk&3]
    // qB: B-frag of Q^T-tile: elem (d,qq) at [qt][qq + 16*(d>>2)][d&3]
    __shared__ _Float16 kA[16][64][4];        // 8 KB
    __shared__ _Float16 vA[16][64][4];        // 8 KB
    __shared__ _Float16 qB[16][64][4];        // 8 KB

    const int n  = blockIdx.x;
    const int p  = n & 15;
    const int bc = n >> 4;
    const int oi = p >> 2;
    const int oj = p & 3;

    const int s   = threadIdx.x;          // token id 0..255
    const int ph  = s >> 2;
    const int pw0 = (s & 3) * DIM;

#pragma unroll
    for (int r = 0; r < 3; ++r)
        sw[r * 256 + s] = w[r * 256 + s];

    const float* xrow = x + ((size_t)bc * HWDIM + (ph + oi)) * HWDIM + pw0 + oj;
    float xr[DIM];
#pragma unroll
    for (int d = 0; d < DIM; ++d) xr[d] = xrow[d];

    __syncthreads();   // sw ready

    // qkv projection (VALU fp32), results written in MFMA frag order (f16)
    const int kt = s >> 4;      // this token's tile
    const int kk = s & 15;      // index within tile
    float qv[DIM], kv[DIM], vv[DIM];
#pragma unroll
    for (int o = 0; o < DIM; ++o) {
        float aq = 0.f, ak = 0.f, av = 0.f;
#pragma unroll
        for (int d = 0; d < DIM; ++d) {
            aq += xr[d] * sw[o * DIM + d];
            ak += xr[d] * sw[(DIM + o) * DIM + d];
            av += xr[d] * sw[(2 * DIM + o) * DIM + d];
        }
        qv[o] = aq * (ATT_SCALE * LOG2E);   // fold scale + log2(e): p = exp2(score)
        kv[o] = ak;
        vv[o] = av;
    }
    // K and Q^T frags: 4x packed 8B writes each
#pragma unroll
    for (int dh = 0; dh < 4; ++dh) {
        half4 kq, qq4;
#pragma unroll
        for (int e = 0; e < 4; ++e) { kq[e] = (_Float16)kv[4 * dh + e]; qq4[e] = (_Float16)qv[4 * dh + e]; }
        *(half4*)&kA[kt][kk + 16 * dh][0] = kq;
        *(half4*)&qB[kt][kk + 16 * dh][0] = qq4;
    }
    // V^T frag: scattered 2B writes (one-time cost)
#pragma unroll
    for (int d = 0; d < DIM; ++d)
        vA[kt][d + 16 * (kk >> 2)][kk & 3] = (_Float16)vv[d];

    __syncthreads();   // frags ready

    const int wave = threadIdx.x >> 6;
    const int lane = threadIdx.x & 63;

    // each wave owns 4 q-tiles: qt = 4*wave + j
    half4 qfrag[4];
#pragma unroll
    for (int j = 0; j < 4; ++j)
        qfrag[j] = *(const half4*)&qB[4 * wave + j][lane][0];

    float4v oacc[4];
    float lpart[4];
#pragma unroll
    for (int j = 0; j < 4; ++j) {
        oacc[j] = (float4v){0.f, 0.f, 0.f, 0.f};
        lpart[j] = 0.f;
    }
    const float4v zf = (float4v){0.f, 0.f, 0.f, 0.f};

    for (int t = 0; t < 16; ++t) {
        const half4 akf = *(const half4*)&kA[t][lane][0];
        const half4 avf = *(const half4*)&vA[t][lane][0];
#pragma unroll
        for (int j = 0; j < 4; ++j) {
            // S^T tile: D[kk][qq] = sum_d K[kk][d] * Q^T[d][qq]
            float4v sfr = __builtin_amdgcn_mfma_f32_16x16x16f16(akf, qfrag[j], zf, 0, 0, 0);
            float p0 = __builtin_amdgcn_exp2f(sfr[0]);
            float p1 = __builtin_amdgcn_exp2f(sfr[1]);
            float p2 = __builtin_amdgcn_exp2f(sfr[2]);
            float p3 = __builtin_amdgcn_exp2f(sfr[3]);
            lpart[j] += (p0 + p1) + (p2 + p3);
            half4 pb;
            pb[0] = (_Float16)p0; pb[1] = (_Float16)p1;
            pb[2] = (_Float16)p2; pb[3] = (_Float16)p3;
            // O^T tile: D[d][qq] += sum_kk V^T[d][kk] * P^T[kk][qq]
            // (P^T C-layout == B-operand layout, used in-register)
            oacc[j] = __builtin_amdgcn_mfma_f32_16x16x16f16(avf, pb, oacc[j], 0, 0, 0);
        }
    }

    // finish softmax denom: l[qq] = butterfly-sum over lane groups {qq, qq+16, qq+32, qq+48}
    const int g = lane >> 4;
#pragma unroll
    for (int j = 0; j < 4; ++j) {
        float lj = lpart[j];
        lj += __shfl_xor(lj, 16, 64);
        lj += __shfl_xor(lj, 32, 64);
        const float rl = 1.f / lj;
        // store O^T frag: element reg r = O[query][d=4g+r], contiguous in r
        const int query = (4 * wave + j) * 16 + (lane & 15);
        float4 v4;
        v4.x = oacc[j][0] * rl;
        v4.y = oacc[j][1] * rl;
        v4.z = oacc[j][2] * rl;
        v4.w = oacc[j][3] * rl;
        *(float4*)(ao + (size_t)n * PLANE + query * DIM + 4 * g) = v4;
    }
}

__global__ __launch_bounds__(256) void ska_fold_pass2(
    const float* __restrict__ ao,     // [NSEQ, 64, 64]
    float* __restrict__ out)          // [B, C, 67, 67]
{
    const int idx = blockIdx.x * 256 + threadIdx.x;
    if (idx >= OUT_TOTAL) return;
    const int w  = idx % HWDIM;
    const int t  = idx / HWDIM;
    const int h  = t % HWDIM;
    const int bc = t / HWDIM;

    const float* base = ao + (size_t)bc * 16 * PLANE;
    float acc = 0.f;
#pragma unroll
    for (int i = 0; i < 4; ++i) {
        const int ph = h - i;
        if (ph < 0 || ph >= 64) continue;
#pragma unroll
        for (int j = 0; j < 4; ++j) {
            const int pw = w - j;
            if (pw < 0 || pw >= 64) continue;
            acc += base[(i * 4 + j) * PLANE + ph * 64 + pw];
        }
    }
    out[idx] = acc;
}

// ---- fallback (atomic fold) if workspace is too small ----
__global__ __launch_bounds__(256) void ska_attn_atomic(
    const float* __restrict__ x, const float* __restrict__ w,
    float* __restrict__ out)
{
    __shared__ float sw[3 * DIM * DIM];
    __shared__ float sk[SEQ][DIM];
    __shared__ float sv[SEQ][DIM];

    const int n = blockIdx.x, p = n & 15, bc = n >> 4, oi = p >> 2, oj = p & 3;
    const int s = threadIdx.x, ph = s >> 2, pw0 = (s & 3) * DIM;

#pragma unroll
    for (int r = 0; r < 3; ++r) sw[r * 256 + s] = w[r * 256 + s];

    const float* xrow = x + ((size_t)bc * HWDIM + (ph + oi)) * HWDIM + pw0 + oj;
    float xr[DIM];
#pragma unroll
    for (int d = 0; d < DIM; ++d) xr[d] = xrow[d];
    __syncthreads();

    float q[DIM];
#pragma unroll
    for (int o = 0; o < DIM; ++o) {
        float aq = 0.f, ak = 0.f, av = 0.f;
#pragma unroll
        for (int d = 0; d < DIM; ++d) {
            aq += xr[d] * sw[o * DIM + d];
            ak += xr[d] * sw[(DIM + o) * DIM + d];
            av += xr[d] * sw[(2 * DIM + o) * DIM + d];
        }
        q[o] = aq * ATT_SCALE; sk[s][o] = ak; sv[s][o] = av;
    }
    __syncthreads();

    float l = 0.f, acc[DIM];
#pragma unroll
    for (int d = 0; d < DIM; ++d) acc[d] = 0.f;
    for (int t = 0; t < SEQ; ++t) {
        float sc = 0.f;
#pragma unroll
        for (int d = 0; d < DIM; ++d) sc += q[d] * sk[t][d];
        const float pe = __expf(sc);
        l += pe;
#pragma unroll
        for (int d = 0; d < DIM; ++d) acc[d] += pe * sv[t][d];
    }
    const float rl = 1.f / l;
    float* obase = out + ((size_t)bc * HWDIM + (ph + oi)) * HWDIM + pw0 + oj;
#pragma unroll
    for (int d = 0; d < DIM; ++d) atomicAdd(&obase[d], acc[d] * rl);
}

extern "C" void kernel_launch(void* const* d_in, const int* in_sizes, int n_in,
                              void* d_out, int out_size, void* d_ws, size_t ws_size,
                              hipStream_t stream) {
    const float* x = (const float*)d_in[0];
    const float* w = (const float*)d_in[1];
    float* out = (float*)d_out;

    const size_t need = (size_t)NSEQ * PLANE * sizeof(float);   // 33.5 MB
    if (ws_size >= need) {
        float* ao = (float*)d_ws;
        ska_attn_pass1<<<NSEQ, 256, 0, stream>>>(x, w, ao);
        ska_fold_pass2<<<(OUT_TOTAL + 255) / 256, 256, 0, stream>>>(ao, out);
    } else {
        hipMemsetAsync(out, 0, (size_t)out_size * sizeof(float), stream);
        ska_attn_atomic<<<NSEQ, 256, 0, stream>>>(x, w, out);
    }
}